// Round 1
// baseline (97.980 us; speedup 1.0000x reference)
//
#include <hip/hip_runtime.h>
#include <hip/hip_bf16.h>

// LocalCausalAttention: B=2, N=2048, D=1024, H=16, DH=64, WINDOW=64
// out = ( softmax(mask(QK^T*0.125)) V ) Wout^T + bout,  QKV = x Wqkv^T + bqkv
//
// Pipeline (all bf16 compute, fp32 accumulate):
//   1. cvt: x, Wqkv, Wout fp32->bf16
//   2. gemm_bt<0>: QKV projection, epilogue scatters to Q(scaled by 0.125)/K/V [B,H,N,64]
//   3. transpose_v: V -> Vt [B,H,64,N]  (makes PV B-operand reads contiguous)
//   4. attn_win: per (b,h,qblock of 64): keys span blocks qb-1..qb (128 keys), MFMA QK^T,
//      in-register masked softmax, P via padded LDS, PV MFMA
//   5. gemm_bt<1>: output projection, fp32 out + bias

typedef __attribute__((ext_vector_type(8))) __bf16 bf16x8;
typedef __attribute__((ext_vector_type(4))) float f32x4;

#define GLOAD16(g, l)                                              \
  __builtin_amdgcn_global_load_lds(                                \
      (const __attribute__((address_space(1))) void*)(g),          \
      (__attribute__((address_space(3))) void*)(l), 16, 0, 0)

#define MFMA16(a, b, c) __builtin_amdgcn_mfma_f32_16x16x32_bf16((a), (b), (c), 0, 0, 0)

// ---------------- fp32 -> bf16 convert ----------------
__global__ __launch_bounds__(256) void cvt_f32_bf16(const float* __restrict__ in,
                                                    __bf16* __restrict__ out, int n) {
  int i = (blockIdx.x * 256 + threadIdx.x) * 8;
  if (i + 8 > n) return;
  f32x4 a = *(const f32x4*)(in + i);
  f32x4 b = *(const f32x4*)(in + i + 4);
  bf16x8 o;
  o[0] = (__bf16)a[0]; o[1] = (__bf16)a[1]; o[2] = (__bf16)a[2]; o[3] = (__bf16)a[3];
  o[4] = (__bf16)b[0]; o[5] = (__bf16)b[1]; o[6] = (__bf16)b[2]; o[7] = (__bf16)b[3];
  *(bf16x8*)(out + i) = o;
}

// ---------------- B^T GEMM: C[m,n] = sum_k A[m,k]*Bw[n,k] + bias[n] ----------------
// 128x128 tile, BK=64, 4 waves (2x2), 16x16x32 MFMA, global_load_lds w/ XOR swizzle.
// MODE 0: scatter bf16 to Q(*0.125)/K/V [B,H,N,64].  MODE 1: fp32 out row-major.
template <int MODE>
__global__ __launch_bounds__(256) void gemm_bt(
    const __bf16* __restrict__ A, const __bf16* __restrict__ Bw,
    const float* __restrict__ bias, int M, int N, int K,
    float* __restrict__ outF,
    __bf16* __restrict__ qo, __bf16* __restrict__ ko, __bf16* __restrict__ vo) {
  __shared__ __align__(16) unsigned char As[128 * 128];  // 128 rows x 64 bf16 (128B)
  __shared__ __align__(16) unsigned char Bs[128 * 128];
  const int tid = threadIdx.x;
  const int lane = tid & 63;
  const int wid = tid >> 6;
  const int wr = wid >> 1, wc = wid & 1;
  const int colL = lane & 15, g = lane >> 4;
  const int m0 = blockIdx.x * 128, n0 = blockIdx.y * 128;

  f32x4 acc[4][4] = {};

  const int nK = K >> 6;
  for (int ks = 0; ks < nK; ++ks) {
    const int k0 = ks << 6;
    __syncthreads();  // prior compute done before overwrite
#pragma unroll
    for (int it = 0; it < 4; ++it) {
      int c = tid + (it << 8);
      int row = c >> 3, p = c & 7;
      int q = p ^ (row & 7);  // inverse-swizzled global source, linear LDS dest
      GLOAD16(A + (size_t)(m0 + row) * K + (k0 + (q << 3)), As + c * 16);
      GLOAD16(Bw + (size_t)(n0 + row) * K + (k0 + (q << 3)), Bs + c * 16);
    }
    __syncthreads();  // drains vmcnt
#pragma unroll
    for (int kk = 0; kk < 2; ++kk) {
      bf16x8 af[4], bf[4];
      const int slot = (kk << 2) + g;
#pragma unroll
      for (int mi = 0; mi < 4; ++mi) {
        int r = (wr << 6) + (mi << 4) + colL;
        af[mi] = *(const bf16x8*)(As + r * 128 + ((slot ^ (r & 7)) << 4));
      }
#pragma unroll
      for (int ni = 0; ni < 4; ++ni) {
        int r = (wc << 6) + (ni << 4) + colL;
        bf[ni] = *(const bf16x8*)(Bs + r * 128 + ((slot ^ (r & 7)) << 4));
      }
#pragma unroll
      for (int mi = 0; mi < 4; ++mi)
#pragma unroll
        for (int ni = 0; ni < 4; ++ni)
          acc[mi][ni] = MFMA16(af[mi], bf[ni], acc[mi][ni]);
    }
  }

  // epilogue: C/D layout col=lane&15, row=(lane>>4)*4+reg (m89-verified)
#pragma unroll
  for (int ni = 0; ni < 4; ++ni) {
    const int Cn = n0 + (wc << 6) + (ni << 4) + colL;
    const float bv = bias[Cn];
    if (MODE == 0) {
      const int sx = Cn >> 10, h = (Cn >> 6) & 15, d = Cn & 63;
      __bf16* dst = (sx == 0) ? qo : (sx == 1 ? ko : vo);
      const float mul = (sx == 0) ? 0.125f : 1.0f;  // fold SCALE into Q (exact pow2)
#pragma unroll
      for (int mi = 0; mi < 4; ++mi) {
#pragma unroll
        for (int j = 0; j < 4; ++j) {
          const int Rm = m0 + (wr << 6) + (mi << 4) + (g << 2) + j;
          const int bb = Rm >> 11, t = Rm & 2047;
          const float v = (acc[mi][ni][j] + bv) * mul;
          dst[(((size_t)bb * 16 + h) * 2048 + t) * 64 + d] = (__bf16)v;
        }
      }
    } else {
#pragma unroll
      for (int mi = 0; mi < 4; ++mi) {
#pragma unroll
        for (int j = 0; j < 4; ++j) {
          const int Rm = m0 + (wr << 6) + (mi << 4) + (g << 2) + j;
          outF[(size_t)Rm * N + Cn] = acc[mi][ni][j] + bv;
        }
      }
    }
  }
}

// ---------------- V [bh, t, 64] -> Vt [bh, 64, t] (64x64 tiles via LDS) ----------------
__global__ __launch_bounds__(256) void transpose_v(const __bf16* __restrict__ Vb,
                                                   __bf16* __restrict__ Vt) {
  const int blk = blockIdx.x;
  const int bh = blk >> 5;          // 32 blocks of 64 tokens per (b,h)
  const int t0 = (blk & 31) << 6;
  __shared__ __align__(16) __bf16 ts[64][72];  // 144B row stride: 16B-aligned, banks spread
  const int tid = threadIdx.x;
  const __bf16* src = Vb + ((size_t)bh * 2048 + t0) * 64;
#pragma unroll
  for (int it = 0; it < 2; ++it) {
    int c = tid + (it << 8);
    int r = c >> 3, q8 = (c & 7) << 3;
    *(bf16x8*)&ts[r][q8] = *(const bf16x8*)(src + r * 64 + q8);
  }
  __syncthreads();
  __bf16* dst = Vt + (size_t)bh * 64 * 2048 + t0;
#pragma unroll
  for (int it = 0; it < 2; ++it) {
    int c = tid + (it << 8);
    int d = c >> 3, j8 = (c & 7) << 3;
    bf16x8 o;
#pragma unroll
    for (int e = 0; e < 8; ++e) o[e] = ts[j8 + e][d];
    *(bf16x8*)(dst + (size_t)d * 2048 + j8) = o;
  }
}

// ---------------- windowed attention ----------------
// grid: (b*16+h)*32 + qb.  4 waves x 16 query rows.  Key tile = 128 tokens starting qb*64-64.
// valid key (tile idx ki) for query (block idx qi): qi < ki <= qi+64, and ki>=64 if qb==0.
__global__ __launch_bounds__(256) void attn_win(const __bf16* __restrict__ Qb,
                                                const __bf16* __restrict__ Kb,
                                                const __bf16* __restrict__ Vt,
                                                __bf16* __restrict__ Ob) {
  const int bh = blockIdx.x >> 5;
  const int qb = blockIdx.x & 31;
  const int b = bh >> 4, h = bh & 15;
  __shared__ __align__(16) unsigned char Qs[64 * 128];
  __shared__ __align__(16) unsigned char Ks[128 * 128];
  __shared__ __align__(16) unsigned char Vs[64 * 256];   // Vt tile [64 d][128 kk]
  __shared__ __align__(16) unsigned char Ps[4 * 16 * 272];  // per-wave P, 272B rows
  const int tid = threadIdx.x;
  const int lane = tid & 63;
  const int w = tid >> 6;
  const int colL = lane & 15, g = lane >> 4;
  const __bf16* Qg = Qb + (size_t)bh * 2048 * 64;
  const __bf16* Kg = Kb + (size_t)bh * 2048 * 64;
  const __bf16* Vg = Vt + (size_t)bh * 64 * 2048;
  const int t0 = qb * 64 - 64;

#pragma unroll
  for (int it = 0; it < 2; ++it) {  // Q: 64 rows x 8 slots
    int c = tid + (it << 8);
    int r = c >> 3, p = c & 7, q = p ^ (r & 7);
    GLOAD16(Qg + (size_t)(qb * 64 + r) * 64 + (q << 3), Qs + c * 16);
  }
#pragma unroll
  for (int it = 0; it < 4; ++it) {  // K: 128 rows x 8 slots
    int c = tid + (it << 8);
    int r = c >> 3, p = c & 7, q = p ^ (r & 7);
    int tok = t0 + r;
    tok = tok < 0 ? 0 : tok;  // qb==0: clamp, masked later
    GLOAD16(Kg + (size_t)tok * 64 + (q << 3), Ks + c * 16);
  }
#pragma unroll
  for (int it = 0; it < 4; ++it) {  // Vt: 64 rows x 16 slots
    int c = tid + (it << 8);
    int r = c >> 4, p = c & 15, q = p ^ (r & 7);
    int tk = t0 + (q << 3);
    tk = tk < 0 ? 0 : tk;  // clamped cols have P=0
    GLOAD16(Vg + (size_t)r * 2048 + tk, Vs + c * 16);
  }
  __syncthreads();

  // QK^T: wave's 16 q-rows x 128 keys
  f32x4 s[8] = {};
  bf16x8 qf[2];
#pragma unroll
  for (int kk = 0; kk < 2; ++kk) {
    int r = (w << 4) + colL;
    int slot = (kk << 2) + g;
    qf[kk] = *(const bf16x8*)(Qs + r * 128 + ((slot ^ (r & 7)) << 4));
  }
#pragma unroll
  for (int ni = 0; ni < 8; ++ni) {
#pragma unroll
    for (int kk = 0; kk < 2; ++kk) {
      int r = (ni << 4) + colL;
      int slot = (kk << 2) + g;
      bf16x8 kf = *(const bf16x8*)(Ks + r * 128 + ((slot ^ (r & 7)) << 4));
      s[ni] = MFMA16(qf[kk], kf, s[ni]);
    }
  }

  // mask + softmax (row = g*4+j, col = ni*16+colL; row-reduce over 16 col-lanes)
  float mx[4], sm[4];
#pragma unroll
  for (int j = 0; j < 4; ++j) mx[j] = -3.0e38f;
#pragma unroll
  for (int ni = 0; ni < 8; ++ni) {
#pragma unroll
    for (int j = 0; j < 4; ++j) {
      const int qi = (w << 4) + (g << 2) + j;
      const int ki = (ni << 4) + colL;
      const bool valid = (ki > qi) && (ki <= qi + 64) && (qb > 0 || ki >= 64);
      if (!valid) s[ni][j] = -3.0e38f;  // finite: avoids inf-inf NaN
      mx[j] = fmaxf(mx[j], s[ni][j]);
    }
  }
#pragma unroll
  for (int j = 0; j < 4; ++j) {
    mx[j] = fmaxf(mx[j], __shfl_xor(mx[j], 1));
    mx[j] = fmaxf(mx[j], __shfl_xor(mx[j], 2));
    mx[j] = fmaxf(mx[j], __shfl_xor(mx[j], 4));
    mx[j] = fmaxf(mx[j], __shfl_xor(mx[j], 8));
    sm[j] = 0.0f;
  }
  unsigned char* ps = Ps + w * (16 * 272);
#pragma unroll
  for (int ni = 0; ni < 8; ++ni) {
#pragma unroll
    for (int j = 0; j < 4; ++j) {
      float p = __expf(s[ni][j] - mx[j]);
      sm[j] += p;
      *(__bf16*)(ps + ((g << 2) + j) * 272 + (((ni << 4) + colL) << 1)) = (__bf16)p;
    }
  }
#pragma unroll
  for (int j = 0; j < 4; ++j) {
    sm[j] += __shfl_xor(sm[j], 1);
    sm[j] += __shfl_xor(sm[j], 2);
    sm[j] += __shfl_xor(sm[j], 4);
    sm[j] += __shfl_xor(sm[j], 8);
  }
  __syncthreads();  // (P is per-wave; barrier is belt-and-braces)

  // PV: O[16,64] = P[16,128] @ Vt^T
  f32x4 o[4] = {};
#pragma unroll
  for (int step = 0; step < 4; ++step) {
    bf16x8 pf = *(const bf16x8*)(ps + colL * 272 + (step << 6) + (g << 4));
#pragma unroll
    for (int dt = 0; dt < 4; ++dt) {
      int r = (dt << 4) + colL;
      int slot = (step << 2) + g;
      bf16x8 vf = *(const bf16x8*)(Vs + r * 256 + ((slot ^ (r & 7)) << 4));
      o[dt] = MFMA16(pf, vf, o[dt]);
    }
  }

  float rinv[4];
#pragma unroll
  for (int j = 0; j < 4; ++j) rinv[j] = 1.0f / sm[j];
#pragma unroll
  for (int dt = 0; dt < 4; ++dt) {
#pragma unroll
    for (int j = 0; j < 4; ++j) {
      const int t = qb * 64 + (w << 4) + (g << 2) + j;
      Ob[((size_t)b * 2048 + t) * 1024 + h * 64 + (dt << 4) + colL] =
          (__bf16)(o[dt][j] * rinv[j]);
    }
  }
}

extern "C" void kernel_launch(void* const* d_in, const int* in_sizes, int n_in,
                              void* d_out, int out_size, void* d_ws, size_t ws_size,
                              hipStream_t stream) {
  const float* x = (const float*)d_in[0];     // [2,2048,1024]
  const float* Wqkv = (const float*)d_in[1];  // [3072,1024]
  const float* bqkv = (const float*)d_in[2];  // [3072]
  const float* Wout = (const float*)d_in[3];  // [1024,1024]
  const float* bout = (const float*)d_in[4];  // [1024]
  float* out = (float*)d_out;                 // [2,2048,1024] fp32

  // workspace layout (bf16 elems): ~56 MB total
  __bf16* xb = (__bf16*)d_ws;             // 4194304
  __bf16* Wqkvb = xb + 4194304;           // 3145728
  __bf16* Woutb = Wqkvb + 3145728;        // 1048576
  __bf16* Qb = Woutb + 1048576;           // 4194304 each: [B,H,2048,64]
  __bf16* Kb = Qb + 4194304;
  __bf16* Vb = Kb + 4194304;
  __bf16* Vtb = Vb + 4194304;             // [B,H,64,2048]
  __bf16* AOb = Vtb + 4194304;            // attn out [B,2048,1024]

  cvt_f32_bf16<<<2048, 256, 0, stream>>>(x, xb, 4194304);
  cvt_f32_bf16<<<1536, 256, 0, stream>>>(Wqkv, Wqkvb, 3145728);
  cvt_f32_bf16<<<512, 256, 0, stream>>>(Wout, Woutb, 1048576);

  gemm_bt<0><<<dim3(32, 24), 256, 0, stream>>>(xb, Wqkvb, bqkv, 4096, 3072, 1024,
                                               nullptr, Qb, Kb, Vb);
  transpose_v<<<1024, 256, 0, stream>>>(Vb, Vtb);
  attn_win<<<1024, 256, 0, stream>>>(Qb, Kb, Vtb, AOb);
  gemm_bt<1><<<dim3(32, 8), 256, 0, stream>>>(AOb, Woutb, bout, 4096, 1024, 1024,
                                              out, nullptr, nullptr, nullptr);
}

// Round 2
// 93.526 us; speedup vs baseline: 1.0476x; 1.0476x over previous
//
#include <hip/hip_runtime.h>
#include <hip/hip_bf16.h>

// LocalCausalAttention: B=2, N=2048, D=1024, H=16, DH=64, WINDOW=64
// out = ( softmax(mask(QK^T*0.125)) V ) Wout^T + bout,  QKV = x Wqkv^T + bqkv
//
// R2: QKV projection moved to 256x256 deep-phase GEMM (T2+T3+T4+T5):
//   - BK=64, 8 waves (2Mx4N), 128KiB LDS double-buffer
//   - 4 phases/K-tile: {12x ds_read_b128 (quadrant frags) ; stage-issue ; s_barrier ;
//     setprio(1) 16xMFMA setprio(0) ; [p3: s_waitcnt vmcnt(0)] ; s_barrier}
//   - staging of tile t+1 issued phases 0-1 into the non-read buffer; single vmcnt(0)
//     per K-tile ~2.5 phases after last issue (counted-style, not drain-after-issue)
//   - raw s_barrier (NOT __syncthreads: that drains vmcnt and kills the pipeline)
// Converts fused into one kernel. Out-proj keeps the 128^2 m97-style kernel
// (N=1024 -> only 64 blocks at 256^2: would underfill 256 CUs).

typedef __attribute__((ext_vector_type(8))) __bf16 bf16x8;
typedef __attribute__((ext_vector_type(4))) float f32x4;

#define GLOAD16(g, l)                                              \
  __builtin_amdgcn_global_load_lds(                                \
      (const __attribute__((address_space(1))) void*)(g),          \
      (__attribute__((address_space(3))) void*)(l), 16, 0, 0)

#define MFMA16(a, b, c) __builtin_amdgcn_mfma_f32_16x16x32_bf16((a), (b), (c), 0, 0, 0)

// ---------------- fused fp32 -> bf16 convert (x, Wqkv, Wout) ----------------
__global__ __launch_bounds__(256) void cvt3(const float* __restrict__ x,
                                            const float* __restrict__ wqkv,
                                            const float* __restrict__ wout,
                                            __bf16* __restrict__ xb,
                                            __bf16* __restrict__ wqkvb,
                                            __bf16* __restrict__ woutb) {
  const int blk = blockIdx.x;
  const float* src;
  __bf16* dst;
  int i;
  if (blk < 2048) {            // x: 4194304 elems
    src = x; dst = xb; i = (blk * 256 + (int)threadIdx.x) * 8;
  } else if (blk < 3584) {     // Wqkv: 3145728 elems
    src = wqkv; dst = wqkvb; i = ((blk - 2048) * 256 + (int)threadIdx.x) * 8;
  } else {                     // Wout: 1048576 elems
    src = wout; dst = woutb; i = ((blk - 3584) * 256 + (int)threadIdx.x) * 8;
  }
  f32x4 a = *(const f32x4*)(src + i);
  f32x4 b = *(const f32x4*)(src + i + 4);
  bf16x8 o;
  o[0] = (__bf16)a[0]; o[1] = (__bf16)a[1]; o[2] = (__bf16)a[2]; o[3] = (__bf16)a[3];
  o[4] = (__bf16)b[0]; o[5] = (__bf16)b[1]; o[6] = (__bf16)b[2]; o[7] = (__bf16)b[3];
  *(bf16x8*)(dst + i) = o;
}

// ---------------- 256^2 deep-phase QKV GEMM ----------------
// C[m,n] = sum_k A[m,k]*Wqkv[n,k] + bqkv[n];  M=4096, N=3072, K=1024 hardcoded.
// Epilogue scatters bf16 to Q(*0.125)/K/V [B,H,2048,64].
__global__ __launch_bounds__(512, 2) void gemm256_qkv(
    const __bf16* __restrict__ A, const __bf16* __restrict__ Bw,
    const float* __restrict__ bias,
    __bf16* __restrict__ qo, __bf16* __restrict__ ko, __bf16* __restrict__ vo) {
  constexpr int K = 1024;
  __shared__ __align__(16) unsigned char As[2][32768];  // [buf][256 rows x 128B]
  __shared__ __align__(16) unsigned char Bs[2][32768];
  const int tid = threadIdx.x;
  const int lane = tid & 63;
  const int wid = tid >> 6;             // 0..7
  const int wm = wid >> 2, wn = wid & 3;  // 2M x 4N wave grid
  const int colL = lane & 15, g = lane >> 4;

  // XCD-aware swizzle: 192 blocks = 24/XCD (192%8==0 -> simple form is bijective)
  int s = blockIdx.x;
  s = (s & 7) * 24 + (s >> 3);
  const int m0 = (s / 12) * 256, n0 = (s % 12) * 256;

  const __bf16* Arow0 = A + (size_t)m0 * K;
  const __bf16* Arow1 = A + (size_t)(m0 + 128) * K;
  const __bf16* Brow0 = Bw + (size_t)n0 * K;
  const __bf16* Brow1 = Bw + (size_t)(n0 + 128) * K;

  // one half-tile (128 rows x 64 cols): linear LDS dest, inverse-swizzled source
  auto stage = [&](const __bf16* src, unsigned char* lds, int k0) {
#pragma unroll
    for (int it = 0; it < 2; ++it) {
      int c = tid + (it << 9);
      int row = c >> 3, pp = c & 7;
      int q = pp ^ (row & 7);
      GLOAD16(src + (size_t)row * K + k0 + (q << 3), lds + c * 16);
    }
  };

  f32x4 acc[8][4] = {};  // per-wave 128x64 output: 8 mi x 4 ni fragments

  // prologue: tile 0 -> buf 0
  stage(Arow0, As[0], 0);
  stage(Arow1, As[0] + 16384, 0);
  stage(Brow0, Bs[0], 0);
  stage(Brow1, Bs[0] + 16384, 0);
  asm volatile("s_waitcnt vmcnt(0)" ::: "memory");
  __builtin_amdgcn_s_barrier();

  for (int t = 0; t < 16; ++t) {
    const unsigned char* Ab = As[t & 1];
    const unsigned char* Bb = Bs[t & 1];
    unsigned char* An = As[(t + 1) & 1];
    unsigned char* Bn = Bs[(t + 1) & 1];
    const int k1 = (t + 1) << 6;
    const bool pf = (t < 15);
#pragma unroll
    for (int p = 0; p < 4; ++p) {  // quadrant p: mi-half p>>1, ni-half p&1
      const int qm = p >> 1, qn = p & 1;
      bf16x8 af[4][2], bq[2][2];
#pragma unroll
      for (int a = 0; a < 4; ++a) {
        const int R = wm * 128 + (qm * 4 + a) * 16 + colL;
#pragma unroll
        for (int kk = 0; kk < 2; ++kk)
          af[a][kk] = *(const bf16x8*)(Ab + R * 128 + ((((kk << 2) + g) ^ (R & 7)) << 4));
      }
#pragma unroll
      for (int b = 0; b < 2; ++b) {
        const int Rn = wn * 64 + (qn * 2 + b) * 16 + colL;
#pragma unroll
        for (int kk = 0; kk < 2; ++kk)
          bq[b][kk] = *(const bf16x8*)(Bb + Rn * 128 + ((((kk << 2) + g) ^ (Rn & 7)) << 4));
      }
      // front-loaded prefetch of tile t+1 into the non-read buffer
      if (p == 0 && pf) { stage(Arow0, An, k1); stage(Arow1, An + 16384, k1); }
      if (p == 1 && pf) { stage(Brow0, Bn, k1); stage(Brow1, Bn + 16384, k1); }
      __builtin_amdgcn_s_barrier();
      __builtin_amdgcn_s_setprio(1);
#pragma unroll
      for (int a = 0; a < 4; ++a)
#pragma unroll
        for (int b = 0; b < 2; ++b) {
          const int mi = qm * 4 + a, ni = qn * 2 + b;
          acc[mi][ni] = MFMA16(af[a][0], bq[b][0], acc[mi][ni]);
          acc[mi][ni] = MFMA16(af[a][1], bq[b][1], acc[mi][ni]);
        }
      __builtin_amdgcn_s_setprio(0);
      if (p == 3) {
        // tile t+1 fully landed (issued >=2.5 phases ago) before next tile reads
        asm volatile("s_waitcnt vmcnt(0)" ::: "memory");
        __builtin_amdgcn_sched_barrier(0);
      }
      __builtin_amdgcn_s_barrier();
    }
  }

  // epilogue: C/D layout col=lane&15, row=(lane>>4)*4+reg; scatter to Q/K/V
#pragma unroll
  for (int ni = 0; ni < 4; ++ni) {
    const int Cn = n0 + wn * 64 + ni * 16 + colL;
    const float bv = bias[Cn];
    const int sx = Cn >> 10, h = (Cn >> 6) & 15, d = Cn & 63;
    __bf16* dst = (sx == 0) ? qo : (sx == 1 ? ko : vo);
    const float mul = (sx == 0) ? 0.125f : 1.0f;  // fold SCALE into Q (exact pow2)
#pragma unroll
    for (int mi = 0; mi < 8; ++mi) {
#pragma unroll
      for (int j = 0; j < 4; ++j) {
        const int Rm = m0 + wm * 128 + mi * 16 + (g << 2) + j;
        const int bb = Rm >> 11, tt = Rm & 2047;
        dst[(((size_t)bb * 16 + h) * 2048 + tt) * 64 + d] = (__bf16)((acc[mi][ni][j] + bv) * mul);
      }
    }
  }
}

// ---------------- 128^2 m97-style GEMM (out-proj): C = A*Bw^T + bias, fp32 out ----
__global__ __launch_bounds__(256) void gemm_bt_out(
    const __bf16* __restrict__ A, const __bf16* __restrict__ Bw,
    const float* __restrict__ bias, int M, int N, int K,
    float* __restrict__ outF) {
  __shared__ __align__(16) unsigned char As[128 * 128];
  __shared__ __align__(16) unsigned char Bs[128 * 128];
  const int tid = threadIdx.x;
  const int lane = tid & 63;
  const int wid = tid >> 6;
  const int wr = wid >> 1, wc = wid & 1;
  const int colL = lane & 15, g = lane >> 4;
  const int m0 = blockIdx.x * 128, n0 = blockIdx.y * 128;

  f32x4 acc[4][4] = {};

  const int nK = K >> 6;
  for (int ks = 0; ks < nK; ++ks) {
    const int k0 = ks << 6;
    __syncthreads();
#pragma unroll
    for (int it = 0; it < 4; ++it) {
      int c = tid + (it << 8);
      int row = c >> 3, p = c & 7;
      int q = p ^ (row & 7);
      GLOAD16(A + (size_t)(m0 + row) * K + (k0 + (q << 3)), As + c * 16);
      GLOAD16(Bw + (size_t)(n0 + row) * K + (k0 + (q << 3)), Bs + c * 16);
    }
    __syncthreads();
#pragma unroll
    for (int kk = 0; kk < 2; ++kk) {
      bf16x8 af[4], bf[4];
      const int slot = (kk << 2) + g;
#pragma unroll
      for (int mi = 0; mi < 4; ++mi) {
        int r = (wr << 6) + (mi << 4) + colL;
        af[mi] = *(const bf16x8*)(As + r * 128 + ((slot ^ (r & 7)) << 4));
      }
#pragma unroll
      for (int ni = 0; ni < 4; ++ni) {
        int r = (wc << 6) + (ni << 4) + colL;
        bf[ni] = *(const bf16x8*)(Bs + r * 128 + ((slot ^ (r & 7)) << 4));
      }
#pragma unroll
      for (int mi = 0; mi < 4; ++mi)
#pragma unroll
        for (int ni = 0; ni < 4; ++ni)
          acc[mi][ni] = MFMA16(af[mi], bf[ni], acc[mi][ni]);
    }
  }

#pragma unroll
  for (int ni = 0; ni < 4; ++ni) {
    const int Cn = n0 + (wc << 6) + (ni << 4) + colL;
    const float bv = bias[Cn];
#pragma unroll
    for (int mi = 0; mi < 4; ++mi) {
#pragma unroll
      for (int j = 0; j < 4; ++j) {
        const int Rm = m0 + (wr << 6) + (mi << 4) + (g << 2) + j;
        outF[(size_t)Rm * N + Cn] = acc[mi][ni][j] + bv;
      }
    }
  }
}

// ---------------- V [bh, t, 64] -> Vt [bh, 64, t] (64x64 tiles via LDS) ----------------
__global__ __launch_bounds__(256) void transpose_v(const __bf16* __restrict__ Vb,
                                                   __bf16* __restrict__ Vt) {
  const int blk = blockIdx.x;
  const int bh = blk >> 5;
  const int t0 = (blk & 31) << 6;
  __shared__ __align__(16) __bf16 ts[64][72];
  const int tid = threadIdx.x;
  const __bf16* src = Vb + ((size_t)bh * 2048 + t0) * 64;
#pragma unroll
  for (int it = 0; it < 2; ++it) {
    int c = tid + (it << 8);
    int r = c >> 3, q8 = (c & 7) << 3;
    *(bf16x8*)&ts[r][q8] = *(const bf16x8*)(src + r * 64 + q8);
  }
  __syncthreads();
  __bf16* dst = Vt + (size_t)bh * 64 * 2048 + t0;
#pragma unroll
  for (int it = 0; it < 2; ++it) {
    int c = tid + (it << 8);
    int d = c >> 3, j8 = (c & 7) << 3;
    bf16x8 o;
#pragma unroll
    for (int e = 0; e < 8; ++e) o[e] = ts[j8 + e][d];
    *(bf16x8*)(dst + (size_t)d * 2048 + j8) = o;
  }
}

// ---------------- windowed attention ----------------
__global__ __launch_bounds__(256) void attn_win(const __bf16* __restrict__ Qb,
                                                const __bf16* __restrict__ Kb,
                                                const __bf16* __restrict__ Vt,
                                                __bf16* __restrict__ Ob) {
  const int bh = blockIdx.x >> 5;
  const int qb = blockIdx.x & 31;
  const int b = bh >> 4, h = bh & 15;
  __shared__ __align__(16) unsigned char Qs[64 * 128];
  __shared__ __align__(16) unsigned char Ks[128 * 128];
  __shared__ __align__(16) unsigned char Vs[64 * 256];
  __shared__ __align__(16) unsigned char Ps[4 * 16 * 272];
  const int tid = threadIdx.x;
  const int lane = tid & 63;
  const int w = tid >> 6;
  const int colL = lane & 15, g = lane >> 4;
  const __bf16* Qg = Qb + (size_t)bh * 2048 * 64;
  const __bf16* Kg = Kb + (size_t)bh * 2048 * 64;
  const __bf16* Vg = Vt + (size_t)bh * 64 * 2048;
  const int t0 = qb * 64 - 64;

#pragma unroll
  for (int it = 0; it < 2; ++it) {
    int c = tid + (it << 8);
    int r = c >> 3, p = c & 7, q = p ^ (r & 7);
    GLOAD16(Qg + (size_t)(qb * 64 + r) * 64 + (q << 3), Qs + c * 16);
  }
#pragma unroll
  for (int it = 0; it < 4; ++it) {
    int c = tid + (it << 8);
    int r = c >> 3, p = c & 7, q = p ^ (r & 7);
    int tok = t0 + r;
    tok = tok < 0 ? 0 : tok;
    GLOAD16(Kg + (size_t)tok * 64 + (q << 3), Ks + c * 16);
  }
#pragma unroll
  for (int it = 0; it < 4; ++it) {
    int c = tid + (it << 8);
    int r = c >> 4, p = c & 15, q = p ^ (r & 7);
    int tk = t0 + (q << 3);
    tk = tk < 0 ? 0 : tk;
    GLOAD16(Vg + (size_t)r * 2048 + tk, Vs + c * 16);
  }
  __syncthreads();

  f32x4 sc[8] = {};
  bf16x8 qf[2];
#pragma unroll
  for (int kk = 0; kk < 2; ++kk) {
    int r = (w << 4) + colL;
    int slot = (kk << 2) + g;
    qf[kk] = *(const bf16x8*)(Qs + r * 128 + ((slot ^ (r & 7)) << 4));
  }
#pragma unroll
  for (int ni = 0; ni < 8; ++ni) {
#pragma unroll
    for (int kk = 0; kk < 2; ++kk) {
      int r = (ni << 4) + colL;
      int slot = (kk << 2) + g;
      bf16x8 kf = *(const bf16x8*)(Ks + r * 128 + ((slot ^ (r & 7)) << 4));
      sc[ni] = MFMA16(qf[kk], kf, sc[ni]);
    }
  }

  float mx[4], sm[4];
#pragma unroll
  for (int j = 0; j < 4; ++j) mx[j] = -3.0e38f;
#pragma unroll
  for (int ni = 0; ni < 8; ++ni) {
#pragma unroll
    for (int j = 0; j < 4; ++j) {
      const int qi = (w << 4) + (g << 2) + j;
      const int ki = (ni << 4) + colL;
      const bool valid = (ki > qi) && (ki <= qi + 64) && (qb > 0 || ki >= 64);
      if (!valid) sc[ni][j] = -3.0e38f;
      mx[j] = fmaxf(mx[j], sc[ni][j]);
    }
  }
#pragma unroll
  for (int j = 0; j < 4; ++j) {
    mx[j] = fmaxf(mx[j], __shfl_xor(mx[j], 1));
    mx[j] = fmaxf(mx[j], __shfl_xor(mx[j], 2));
    mx[j] = fmaxf(mx[j], __shfl_xor(mx[j], 4));
    mx[j] = fmaxf(mx[j], __shfl_xor(mx[j], 8));
    sm[j] = 0.0f;
  }
  unsigned char* ps = Ps + w * (16 * 272);
#pragma unroll
  for (int ni = 0; ni < 8; ++ni) {
#pragma unroll
    for (int j = 0; j < 4; ++j) {
      float p = __expf(sc[ni][j] - mx[j]);
      sm[j] += p;
      *(__bf16*)(ps + ((g << 2) + j) * 272 + (((ni << 4) + colL) << 1)) = (__bf16)p;
    }
  }
#pragma unroll
  for (int j = 0; j < 4; ++j) {
    sm[j] += __shfl_xor(sm[j], 1);
    sm[j] += __shfl_xor(sm[j], 2);
    sm[j] += __shfl_xor(sm[j], 4);
    sm[j] += __shfl_xor(sm[j], 8);
  }
  __syncthreads();

  f32x4 o[4] = {};
#pragma unroll
  for (int step = 0; step < 4; ++step) {
    bf16x8 pf = *(const bf16x8*)(ps + colL * 272 + (step << 6) + (g << 4));
#pragma unroll
    for (int dt = 0; dt < 4; ++dt) {
      int r = (dt << 4) + colL;
      int slot = (step << 2) + g;
      bf16x8 vf = *(const bf16x8*)(Vs + r * 256 + ((slot ^ (r & 7)) << 4));
      o[dt] = MFMA16(pf, vf, o[dt]);
    }
  }

  float rinv[4];
#pragma unroll
  for (int j = 0; j < 4; ++j) rinv[j] = 1.0f / sm[j];
#pragma unroll
  for (int dt = 0; dt < 4; ++dt) {
#pragma unroll
    for (int j = 0; j < 4; ++j) {
      const int t = qb * 64 + (w << 4) + (g << 2) + j;
      Ob[((size_t)b * 2048 + t) * 1024 + h * 64 + (dt << 4) + colL] =
          (__bf16)(o[dt][j] * rinv[j]);
    }
  }
}

extern "C" void kernel_launch(void* const* d_in, const int* in_sizes, int n_in,
                              void* d_out, int out_size, void* d_ws, size_t ws_size,
                              hipStream_t stream) {
  const float* x = (const float*)d_in[0];     // [2,2048,1024]
  const float* Wqkv = (const float*)d_in[1];  // [3072,1024]
  const float* bqkv = (const float*)d_in[2];  // [3072]
  const float* Wout = (const float*)d_in[3];  // [1024,1024]
  const float* bout = (const float*)d_in[4];  // [1024]
  float* out = (float*)d_out;                 // [2,2048,1024] fp32

  __bf16* xb = (__bf16*)d_ws;             // 4194304
  __bf16* Wqkvb = xb + 4194304;           // 3145728
  __bf16* Woutb = Wqkvb + 3145728;        // 1048576
  __bf16* Qb = Woutb + 1048576;           // 4194304 each: [B,H,2048,64]
  __bf16* Kb = Qb + 4194304;
  __bf16* Vb = Kb + 4194304;
  __bf16* Vtb = Vb + 4194304;             // [B,H,64,2048]
  __bf16* AOb = Vtb + 4194304;            // attn out [B,2048,1024]

  cvt3<<<4096, 256, 0, stream>>>(x, Wqkv, Wout, xb, Wqkvb, Woutb);
  gemm256_qkv<<<192, 512, 0, stream>>>(xb, Wqkvb, bqkv, Qb, Kb, Vb);
  transpose_v<<<1024, 256, 0, stream>>>(Vb, Vtb);
  attn_win<<<1024, 256, 0, stream>>>(Qb, Kb, Vtb, AOb);
  gemm_bt_out<<<dim3(32, 8), 256, 0, stream>>>(AOb, Woutb, bout, 4096, 1024, 1024, out);
}